// Round 15
// baseline (251.140 us; speedup 1.0000x reference)
//
#include <hip/hip_runtime.h>
#include <hip/hip_bf16.h>
#include <cstdint>
#include <cstddef>

typedef __bf16 bf16;
typedef __attribute__((ext_vector_type(4))) __bf16 bf16x4;
typedef __attribute__((ext_vector_type(8))) __bf16 bf16x8;
typedef __attribute__((ext_vector_type(4))) float f32x4;
typedef __attribute__((ext_vector_type(16))) float f32x16;
typedef __attribute__((ext_vector_type(4))) float floatx4;
typedef __attribute__((ext_vector_type(2))) unsigned uint2_t;
typedef __attribute__((ext_vector_type(4))) unsigned uint4_t;

// Problem constants
#define NTOK 8192
#define DIMM 1152
#define NH   16
#define HD   72
#define SEGS 4
#define SEGL 2048

__device__ __forceinline__ void gload16(const void* gsrc, void* ldst) {
  __builtin_amdgcn_global_load_lds(
      (const __attribute__((address_space(1))) void*)gsrc,
      (__attribute__((address_space(3))) void*)ldst,
      16, 0, 0);
}

// single-instruction pack: low16 = bf16(a), high16 = bf16(b)
__device__ __forceinline__ unsigned cvtpk(float a, float b) {
  unsigned r;
  asm volatile("v_cvt_pk_bf16_f32 %0, %1, %2" : "=v"(r) : "v"(a), "v"(b));
  return r;
}

// ---- fused prep: [0,4608) f32->bf16 cvt of hs; then two transposed weights ----
__global__ __launch_bounds__(256) void k_prep(const float* __restrict__ hs,
                                              bf16* __restrict__ hsb,
                                              const float* __restrict__ wq,
                                              bf16* __restrict__ wqT,
                                              const float* __restrict__ wp,
                                              bf16* __restrict__ wpT) {
  __shared__ bf16 tile[64][73];
  const int b = blockIdx.x, t = threadIdx.x;
  if (b < 4608) {
    int i = b * 256 + t;
    const floatx4* s = (const floatx4*)hs + (size_t)i * 2;
    floatx4 a = s[0], c = s[1];
    uint4_t o;
    o[0] = cvtpk(a.x, a.y);
    o[1] = cvtpk(a.z, a.w);
    o[2] = cvtpk(c.x, c.y);
    o[3] = cvtpk(c.z, c.w);
    *((uint4_t*)hsb + i) = o;
    return;
  }
  const float* src; bf16* dst; int R, C, bx, by;
  if (b < 4608 + 1008) {
    int idx = b - 4608;
    src = wq; dst = wqT; R = 1152; C = 3456; bx = idx % 56; by = idx / 56;
  } else {
    int idx = b - 5616;
    src = wp; dst = wpT; R = 1152; C = 1152; bx = idx % 18; by = idx / 18;
  }
  int bc = bx * 64, br = by * 64;
#pragma unroll
  for (int i = 0; i < 16; i++) {
    int idx = i * 256 + t;
    int r = idx >> 6, c = idx & 63;
    float v = (bc + c < C) ? src[(size_t)(br + r) * C + bc + c] : 0.f;
    tile[c][r] = (bf16)v;
  }
  __syncthreads();
#pragma unroll
  for (int i = 0; i < 16; i++) {
    int idx = i * 256 + t;
    int r = idx >> 6, c = idx & 63;
    dst[(size_t)(bc + r) * R + br + c] = tile[r][c];
  }
}

// ==== QKV GEMM 256x256: per-K-tile validate + partial-lgkm MFMA clusters ======
// 8 waves (2M x 4N), per-wave C = 128x64. LDS [2dbuf][2half][128][64]/operand.
// Per tile: vmcnt(8) -> barrier(V) -> 12 reads -> lgkm(4) -> c1 -> 12 reads ->
// lgkm(12) -> c2 -> lgkm(4) -> c3 -> lgkm(0) -> c4 -> barrier(R) -> stage t+2.
// Data mappings identical to the verified round-14 kernel; only order/sync.
__global__ __launch_bounds__(512, 2) void k_gemmF(const bf16* __restrict__ A,
                                                  const bf16* __restrict__ Bt,
                                                  const float* __restrict__ bias,
                                                  bf16* __restrict__ Cout,
                                                  int M, int Nreal, int K, int gx) {
  __shared__ bf16 sA[2][2][128 * 64];   // 64 KB
  __shared__ bf16 sB[2][2][128 * 64];   // 64 KB
  const int t = threadIdx.x, wave = t >> 6, lane = t & 63;
  const int lr = lane & 15, lg = lane >> 4;
  const int nwg = gridDim.x, bid = blockIdx.x;
  const int swz = (bid & 7) * (nwg >> 3) + (bid >> 3);
  const int bx = swz % gx, by = swz / gx;
  const int m0 = by * 256, n0 = bx * 256;
  const int wr = wave >> 2, wc = wave & 3;
  const int bh = wc >> 1, bro = (wc & 1) * 64;
  const int NS = K >> 6;                // 18 K-tiles of 64

  f32x4 acc[8][4];
#pragma unroll
  for (int i = 0; i < 8; i++)
#pragma unroll
    for (int j = 0; j < 4; j++)
#pragma unroll
      for (int q = 0; q < 4; q++) acc[i][j][q] = 0.f;

  const bf16* Ab = A + (size_t)m0 * K;
  const bf16* Bb = Bt + (size_t)n0 * K;
  const int glsw8 = (((t & 7) ^ ((t >> 3) & 7)) * 8);
  const bf16* Asrc[2][2];               // [half][p]
  const bf16* Bsrc[2][2];
#pragma unroll
  for (int h = 0; h < 2; h++)
#pragma unroll
    for (int p = 0; p < 2; p++) {
      Asrc[h][p] = Ab + (size_t)(h * 128 + p * 64 + (t >> 3)) * K + glsw8;
      Bsrc[h][p] = Bb + (size_t)(h * 128 + p * 64 + (t >> 3)) * K + glsw8;
    }
  auto STA = [&](int d2, int h, int ttt) {
    gload16(Asrc[h][0] + (size_t)ttt * 64, (char*)&sA[d2][h][0] + t * 16);
    gload16(Asrc[h][1] + (size_t)ttt * 64, (char*)&sA[d2][h][0] + 8192 + t * 16);
  };
  auto STB = [&](int d2, int h, int ttt) {
    gload16(Bsrc[h][0] + (size_t)ttt * 64, (char*)&sB[d2][h][0] + t * 16);
    gload16(Bsrc[h][1] + (size_t)ttt * 64, (char*)&sB[d2][h][0] + 8192 + t * 16);
  };
  // fragment read K-group offsets (elements), swizzled: row&7 == lr&7
  const int ga[2] = { ((0 + lg) ^ (lr & 7)) * 8, ((4 + lg) ^ (lr & 7)) * 8 };

  // prologue: tiles 0 and 1 (8 loads each, FIFO)
  STB(0, 0, 0); STB(0, 1, 0); STA(0, 0, 0); STA(0, 1, 0);
  STB(1, 0, 1); STB(1, 1, 1); STA(1, 0, 1); STA(1, 1, 1);

  for (int tt = 0; tt < NS; ++tt) {
    const int d = tt & 1;
    if (tt + 1 < NS) {
      asm volatile("s_waitcnt vmcnt(8)" ::: "memory");
    } else {
      asm volatile("s_waitcnt vmcnt(0)" ::: "memory");
    }
    __builtin_amdgcn_s_barrier();           // V_t : tile t resident
    __builtin_amdgcn_sched_barrier(0);
    bf16x8 av0[4], av1[4], av2[4], av3[4], bv0[4], bv1[4];
    // T1: 12 reads (kk=0)
#pragma unroll
    for (int mi = 0; mi < 4; mi++)
      av0[mi] = *(const bf16x8*)&sA[d][wr][(mi * 16 + lr) * 64 + ga[0]];
#pragma unroll
    for (int ni = 0; ni < 4; ni++)
      bv0[ni] = *(const bf16x8*)&sB[d][bh][(bro + ni * 16 + lr) * 64 + ga[0]];
#pragma unroll
    for (int mi = 0; mi < 4; mi++)
      av1[mi] = *(const bf16x8*)&sA[d][wr][(64 + mi * 16 + lr) * 64 + ga[0]];
    asm volatile("s_waitcnt lgkmcnt(4)" ::: "memory");   // av0+bv0 done
    __builtin_amdgcn_sched_barrier(0);
    __builtin_amdgcn_s_setprio(1);
#pragma unroll
    for (int mi = 0; mi < 4; mi++)
#pragma unroll
      for (int ni = 0; ni < 4; ni++)
        acc[mi][ni] = __builtin_amdgcn_mfma_f32_16x16x32_bf16(av0[mi], bv0[ni], acc[mi][ni], 0, 0, 0);
    __builtin_amdgcn_s_setprio(0);
    __builtin_amdgcn_sched_barrier(0);
    // T2: 12 reads (kk=1) — latency hides under c2
#pragma unroll
    for (int mi = 0; mi < 4; mi++)
      av2[mi] = *(const bf16x8*)&sA[d][wr][(mi * 16 + lr) * 64 + ga[1]];
#pragma unroll
    for (int ni = 0; ni < 4; ni++)
      bv1[ni] = *(const bf16x8*)&sB[d][bh][(bro + ni * 16 + lr) * 64 + ga[1]];
#pragma unroll
    for (int mi = 0; mi < 4; mi++)
      av3[mi] = *(const bf16x8*)&sA[d][wr][(64 + mi * 16 + lr) * 64 + ga[1]];
    asm volatile("s_waitcnt lgkmcnt(12)" ::: "memory");  // all of T1 done
    __builtin_amdgcn_sched_barrier(0);
    __builtin_amdgcn_s_setprio(1);
#pragma unroll
    for (int mi = 0; mi < 4; mi++)
#pragma unroll
      for (int ni = 0; ni < 4; ni++)
        acc[4 + mi][ni] = __builtin_amdgcn_mfma_f32_16x16x32_bf16(av1[mi], bv0[ni], acc[4 + mi][ni], 0, 0, 0);
    __builtin_amdgcn_s_setprio(0);
    __builtin_amdgcn_sched_barrier(0);
    asm volatile("s_waitcnt lgkmcnt(4)" ::: "memory");   // av2+bv1 done
    __builtin_amdgcn_sched_barrier(0);
    __builtin_amdgcn_s_setprio(1);
#pragma unroll
    for (int mi = 0; mi < 4; mi++)
#pragma unroll
      for (int ni = 0; ni < 4; ni++)
        acc[mi][ni] = __builtin_amdgcn_mfma_f32_16x16x32_bf16(av2[mi], bv1[ni], acc[mi][ni], 0, 0, 0);
    __builtin_amdgcn_s_setprio(0);
    __builtin_amdgcn_sched_barrier(0);
    asm volatile("s_waitcnt lgkmcnt(0)" ::: "memory");   // av3 done
    __builtin_amdgcn_sched_barrier(0);
    __builtin_amdgcn_s_setprio(1);
#pragma unroll
    for (int mi = 0; mi < 4; mi++)
#pragma unroll
      for (int ni = 0; ni < 4; ni++)
        acc[4 + mi][ni] = __builtin_amdgcn_mfma_f32_16x16x32_bf16(av3[mi], bv1[ni], acc[4 + mi][ni], 0, 0, 0);
    __builtin_amdgcn_s_setprio(0);
    __builtin_amdgcn_s_barrier();           // R_t : all reads of dbuf d landed
    __builtin_amdgcn_sched_barrier(0);
    if (tt + 2 < NS) {                      // stage tile t+2 into dbuf d (WAR-safe)
      STB(d, 0, tt + 2); STB(d, 1, tt + 2);
      STA(d, 0, tt + 2); STA(d, 1, tt + 2);
    }
  }

  // epilogue: guarded store (cols < Nreal), bias add
#pragma unroll
  for (int mi = 0; mi < 8; ++mi)
#pragma unroll
    for (int ni = 0; ni < 4; ++ni) {
      int col = n0 + wc * 64 + ni * 16 + lr;
      if (col < Nreal) {
        float bc_ = bias[col];
#pragma unroll
        for (int j = 0; j < 4; j++) {
          int row = m0 + wr * 128 + mi * 16 + lg * 4 + j;
          Cout[(size_t)row * Nreal + col] = (bf16)(acc[mi][ni][j] + bc_);
        }
      }
    }
}

// ---- pipelined bf16 GEMM (proj): 3-slot LDS ring, one barrier per 32-K step ---
template <int BM, int BN, int MI, int NI, int THREADS, bool OUT_F32, int MW>
__global__ __launch_bounds__(THREADS, MW) void k_gemmP(const bf16* __restrict__ A,
                                                       const bf16* __restrict__ Bt,
                                                       const float* __restrict__ bias,
                                                       void* __restrict__ Cout,
                                                       int M, int Nreal, int K, int gx) {
  __shared__ bf16 sA[3][BM * 32];
  __shared__ bf16 sB[3][BN * 32];
  constexpr int WN = BN / (NI * 16);
  constexpr int nA = (BM * 4) / THREADS;
  constexpr int nB = (BN * 4) / THREADS;
  constexpr int NLD = nA + nB;
  static_assert(NLD == 3 || NLD == 4 || NLD == 6, "vmcnt literal");
  const int t = threadIdx.x, wave = t >> 6, lane = t & 63;
  const int lr = lane & 15, lg = lane >> 4;
  const int nwg = gridDim.x, bid = blockIdx.x;
  const int swz = (bid & 7) * (nwg >> 3) + (bid >> 3);
  const int bx = swz % gx, by = swz / gx;
  const int m0 = by * BM, n0 = bx * BN;
  const int wr = wave / WN, wc = wave % WN;
  const int NS = K >> 5;

  f32x4 acc[MI][NI];
#pragma unroll
  for (int i = 0; i < MI; i++)
#pragma unroll
    for (int j = 0; j < NI; j++)
#pragma unroll
      for (int q = 0; q < 4; q++) acc[i][j][q] = 0.f;

  const bf16* Ab = A + (size_t)m0 * K;
  const bf16* Bb = Bt + (size_t)n0 * K;
  const int glsw = ((t & 3) ^ ((t >> 3) & 3)) * 8;
  const int rbase = t >> 2;

  auto STAGE = [&](int slot, int k0) {
#pragma unroll
    for (int p = 0; p < nA; ++p)
      gload16(Ab + (size_t)(rbase + p * (THREADS / 4)) * K + k0 + glsw,
              (char*)&sA[slot][0] + p * (THREADS * 16) + wave * 1024);
#pragma unroll
    for (int p = 0; p < nB; ++p)
      gload16(Bb + (size_t)(rbase + p * (THREADS / 4)) * K + k0 + glsw,
              (char*)&sB[slot][0] + p * (THREADS * 16) + wave * 1024);
  };

  const int swz4 = (lr >> 1) & 3;
  const int aoff = (wr * MI * 16 + lr) * 32 + ((lg ^ swz4) * 8);
  const int boff = (wc * NI * 16 + lr) * 32 + ((lg ^ swz4) * 8);

  STAGE(0, 0);
  STAGE(1, 32);

  int slot = 0;
  for (int j = 0; j < NS; ++j) {
    if (j == NS - 1) {
      asm volatile("s_waitcnt vmcnt(0)" ::: "memory");
    } else if constexpr (NLD == 3) {
      asm volatile("s_waitcnt vmcnt(3)" ::: "memory");
    } else if constexpr (NLD == 4) {
      asm volatile("s_waitcnt vmcnt(4)" ::: "memory");
    } else {
      asm volatile("s_waitcnt vmcnt(6)" ::: "memory");
    }
    __builtin_amdgcn_s_barrier();
    __builtin_amdgcn_sched_barrier(0);
    bf16x8 av[MI], bv[NI];
#pragma unroll
    for (int mi = 0; mi < MI; mi++)
      av[mi] = *(const bf16x8*)&sA[slot][aoff + mi * 512];
#pragma unroll
    for (int ni = 0; ni < NI; ni++)
      bv[ni] = *(const bf16x8*)&sB[slot][boff + ni * 512];
    asm volatile("s_waitcnt lgkmcnt(0)" ::: "memory");
    __builtin_amdgcn_sched_barrier(0);
    if (j + 2 < NS) {
      int s2 = slot + 2; if (s2 >= 3) s2 -= 3;
      STAGE(s2, (j + 2) * 32);
    }
    __builtin_amdgcn_s_setprio(1);
#pragma unroll
    for (int mi = 0; mi < MI; mi++)
#pragma unroll
      for (int ni = 0; ni < NI; ni++)
        acc[mi][ni] = __builtin_amdgcn_mfma_f32_16x16x32_bf16(av[mi], bv[ni], acc[mi][ni], 0, 0, 0);
    __builtin_amdgcn_s_setprio(0);
    if (++slot == 3) slot = 0;
  }

#pragma unroll
  for (int mi = 0; mi < MI; ++mi)
#pragma unroll
    for (int ni = 0; ni < NI; ++ni) {
      int col = n0 + wc * NI * 16 + ni * 16 + lr;
      if (col < Nreal) {
        float bc_ = bias[col];
#pragma unroll
        for (int j = 0; j < 4; j++) {
          int row = m0 + wr * MI * 16 + mi * 16 + lg * 4 + j;
          float v = acc[mi][ni][j] + bc_;
          if (OUT_F32)
            ((float*)Cout)[(size_t)row * Nreal + col] = v;
          else
            ((bf16*)Cout)[(size_t)row * Nreal + col] = (bf16)v;
        }
      }
    }
}

// ---- fused RoPE(vectorized) + V repack --------------------------------------
__global__ __launch_bounds__(256) void k_ropev(const bf16* __restrict__ qkv,
                                               const float* __restrict__ cs,
                                               const float* __restrict__ sn,
                                               bf16* __restrict__ Qp,
                                               bf16* __restrict__ Kp,
                                               bf16* __restrict__ Vt) {
  __shared__ bf16 tl[64][80];
  const int bid = blockIdx.x, t = threadIdx.x;
  if (bid < 2048) {
    const float QS = 0.17002323f;  // log2(e)/sqrt(72)
    const int n0 = bid * 4;
#pragma unroll
    for (int it = 0; it < 6; ++it) {
      int idx = it * 256 + t;
      int tok = idx / 384;
      int r = idx - tok * 384;
      int which = r / 192;
      int r2 = r - which * 192;
      int h = r2 / 12;
      int d0 = (r2 - h * 12) * 8;
      int n = n0 + tok;
      bf16* dst = which ? Kp : Qp;
      size_t ob = ((((size_t)((n >> 11) * NH + h)) * 3 + (d0 >> 5)) * SEGL +
                   (n & 2047)) * 32 + (d0 & 31);
      if (d0 >= HD) {                     // pad region d = 72..95
        uint4_t z = {0u, 0u, 0u, 0u};
        *(uint4_t*)&dst[ob] = z;
        continue;
      }
      const bf16* rowp = qkv + (size_t)n * (3 * DIMM) + which * DIMM + h * HD;
      bf16x8 xv = *(const bf16x8*)&rowp[d0];
      float ov[8];
      if (d0 == 32) {
        bf16x4 a = *(const bf16x4*)&rowp[68];
        bf16x4 b = *(const bf16x4*)&rowp[0];
#pragma unroll
        for (int j = 0; j < 4; j++) { ov[j] = -(float)a[j]; ov[j + 4] = (float)b[j]; }
      } else if (d0 < 32) {
        bf16x4 a = *(const bf16x4*)&rowp[d0 + 36];
        bf16x4 b = *(const bf16x4*)&rowp[d0 + 40];
#pragma unroll
        for (int j = 0; j < 4; j++) { ov[j] = -(float)a[j]; ov[j + 4] = -(float)b[j]; }
      } else {
        bf16x4 a = *(const bf16x4*)&rowp[d0 - 36];
        bf16x4 b = *(const bf16x4*)&rowp[d0 - 32];
#pragma unroll
        for (int j = 0; j < 4; j++) { ov[j] = (float)a[j]; ov[j + 4] = (float)b[j]; }
      }
      const float* cr = cs + (size_t)n * HD + d0;
      const float* sr = sn + (size_t)n * HD + d0;
      floatx4 c0 = *(const floatx4*)cr, c1 = *(const floatx4*)(cr + 4);
      floatx4 s0 = *(const floatx4*)sr, s1 = *(const floatx4*)(sr + 4);
      float vv[8];
#pragma unroll
      for (int j = 0; j < 4; j++) {
        vv[j] = (float)xv[j] * c0[j] + ov[j] * s0[j];
        vv[j + 4] = (float)xv[j + 4] * c1[j] + ov[j + 4] * s1[j];
      }
      if (!which) {
#pragma unroll
        for (int j = 0; j < 8; j++) vv[j] *= QS;
      }
      uint4_t w;
      w[0] = cvtpk(vv[0], vv[1]);
      w[1] = cvtpk(vv[2], vv[3]);
      w[2] = cvtpk(vv[4], vv[5]);
      w[3] = cvtpk(vv[6], vv[7]);
      *(uint4_t*)&dst[ob] = w;
    }
  } else {
    int idx2 = bid - 2048;
    int s = idx2 >> 9, h = (idx2 >> 5) & 15, l0 = (idx2 & 31) * 64;
    for (int idx = t; idx < 64 * HD; idx += 256) {
      int l = idx / HD, d = idx - l * HD;
      tl[l][d] = qkv[(size_t)(s * SEGL + l0 + l) * (3 * DIMM) + 2 * DIMM + h * HD + d];
    }
    __syncthreads();
    for (int idx = t; idx < 96 * 64; idx += 256) {
      int d = idx >> 6, l = idx & 63;
      bf16 v = (d < HD) ? tl[l][d] : ((d == HD) ? (bf16)1.f : (bf16)0.f);
      Vt[((size_t)(s * NH + h) * 96 + d) * SEGL + l0 + l] = v;
    }
  }
}

// ---------------- flash attention (round-8 structure) --------------------------
__global__ __launch_bounds__(256, 2) void k_attn(const bf16* __restrict__ Qg,
                                                 const bf16* __restrict__ Kg,
                                                 const bf16* __restrict__ Vg,
                                                 bf16* __restrict__ Oo) {
  __shared__ bf16 sK[2][3 * 64 * 32];   // 2 x 12 KB
  __shared__ bf16 sV[2][96 * 64];       // 2 x 12 KB
  const int t = threadIdx.x, wave = t >> 6, lane = t & 63;
  const int c = lane & 31, hi = lane >> 5;
  const int bid = blockIdx.x;
  const int g = ((bid >> 6) << 3) | (bid & 7);   // group 0..63 (xcd = g&7)
  const int qt = (bid >> 3) & 7;
  const int s = g >> 4, h = g & 15, q0 = qt * 256;
  const bf16* Qb = Qg + (size_t)(s * NH + h) * 3 * SEGL * 32;
  const bf16* Kb = Kg + (size_t)(s * NH + h) * 3 * SEGL * 32;
  const bf16* Vb = Vg + (size_t)(s * NH + h) * 96 * SEGL;

  const bf16* kq[3];
  const bf16* vq[3];
#pragma unroll
  for (int i = 0; i < 3; i++) {
    int ch = wave * 3 + i;
    int kk = ch >> 2;
    int r = (ch & 3) * 16 + (lane >> 2);
    int gg = (lane & 3) ^ ((r >> 1) & 3);
    kq[i] = Kb + (size_t)kk * (SEGL * 32) + (size_t)r * 32 + gg * 8;
    int rv = ch * 8 + (lane >> 3);
    int gv = (lane & 7) ^ (rv & 7);
    vq[i] = Vb + (size_t)rv * SEGL + gv * 8;
  }

  bf16x8 Qf[2][5];
#pragma unroll
  for (int sni = 0; sni < 2; sni++)
#pragma unroll
    for (int kk = 0; kk < 5; kk++) {
      int qr = q0 + wave * 64 + sni * 32 + c;
      Qf[sni][kk] = *(const bf16x8*)&Qb[(size_t)(kk >> 1) * (SEGL * 32) +
                                        (size_t)qr * 32 + ((kk & 1) * 2 + hi) * 8];
    }

#pragma unroll
  for (int i = 0; i < 3; i++) {
    gload16(kq[i], (char*)sK[0] + (wave * 3 + i) * 1024);
    gload16(vq[i], (char*)sV[0] + (wave * 3 + i) * 1024);
    kq[i] += 2048;
    vq[i] += 64;
  }
  __syncthreads();

  f32x16 accO[3][2];
#pragma unroll
  for (int df = 0; df < 3; df++)
#pragma unroll
    for (int sni = 0; sni < 2; sni++)
#pragma unroll
      for (int r = 0; r < 16; r++) accO[df][sni][r] = 0.f;
  f32x16 ZC;
#pragma unroll
  for (int r = 0; r < 16; r++) ZC[r] = 0.f;

  int cur = 0;
  for (int tile = 0; tile < 32; ++tile) {
    if (tile + 1 < 32) {
#pragma unroll
      for (int i = 0; i < 3; i++) {
        gload16(kq[i], (char*)sK[cur ^ 1] + (wave * 3 + i) * 1024);
        gload16(vq[i], (char*)sV[cur ^ 1] + (wave * 3 + i) * 1024);
        kq[i] += 2048;
        vq[i] += 64;
      }
    }

    // ===== S^T = K · Q =====
    f32x16 S[2][2];
    __builtin_amdgcn_s_setprio(1);
#pragma unroll
    for (int kk = 0; kk < 5; kk++) {
      bf16x8 Kf[2];
#pragma unroll
      for (int smi = 0; smi < 2; smi++) {
        int kr = smi * 32 + c;
        int gg = (((kk & 1) * 2 + hi) ^ ((kr >> 1) & 3));
        Kf[smi] = *(const bf16x8*)&sK[cur][(kk >> 1) * 2048 + kr * 32 + gg * 8];
      }
#pragma unroll
      for (int smi = 0; smi < 2; smi++)
#pragma unroll
        for (int sni = 0; sni < 2; sni++)
          S[smi][sni] = __builtin_amdgcn_mfma_f32_32x32x16_bf16(
              Kf[smi], Qf[sni][kk], kk ? S[smi][sni] : ZC, 0, 0, 0);
    }
    __builtin_amdgcn_s_setprio(0);

    // ===== O^T += V^T · P^T =====
    __builtin_amdgcn_s_setprio(1);
#pragma unroll
    for (int kk = 0; kk < 4; kk++) {
      bf16x8 Vf[3];
#pragma unroll
      for (int df = 0; df < 3; df++) {
        int dr = df * 32 + c;
        int gg = ((kk * 2 + hi) ^ (dr & 7));
        Vf[df] = *(const bf16x8*)&sV[cur][dr * 64 + gg * 8];
      }
#pragma unroll
      for (int sni = 0; sni < 2; sni++) {
        const int smi = kk >> 1;
        const int base = (kk & 1) * 8;
        unsigned u0 = cvtpk(__builtin_amdgcn_exp2f(S[smi][sni][base + 0]),
                            __builtin_amdgcn_exp2f(S[smi][sni][base + 1]));
        unsigned u1 = cvtpk(__builtin_amdgcn_exp2f(S[smi][sni][base + 2]),
                            __builtin_amdgcn_exp2f(S[smi][sni][base + 3]));
        unsigned u2 = cvtpk(__builtin_amdgcn_exp2f(S[smi][sni][base + 4]),
                            __builtin_amdgcn_exp2f(S[smi][sni][base + 5]));
        unsigned u3 = cvtpk(__builtin_amdgcn_exp2f(S[smi][sni][base + 6]),
                            __builtin_amdgcn_exp2f(S[smi][sni][base + 7]));
        asm volatile("v_permlane32_swap_b32 %0, %1" : "+v"(u0), "+v"(u2));
        asm volatile("v_permlane32_swap_b32 %0, %1" : "+v"(u1), "+v"(u3));
        union { bf16x8 v; unsigned u[4]; } pb;
        pb.u[0] = u0; pb.u[1] = u1; pb.u[2] = u2; pb.u[3] = u3;
#pragma unroll
        for (int df = 0; df < 3; df++)
          accO[df][sni] = __builtin_amdgcn_mfma_f32_32x32x16_bf16(Vf[df], pb.v, accO[df][sni], 0, 0, 0);
      }
    }
    __builtin_amdgcn_s_setprio(0);

    __syncthreads();
    cur ^= 1;
  }

  // ===== write O (token-major), 8 B packed stores =====
#pragma unroll
  for (int sni = 0; sni < 2; sni++) {
    float lown = accO[2][sni][4];
    float lv = lown + __shfl_xor(lown, 32, 64);
    float inv = 1.f / lv;
    int token = s * SEGL + q0 + wave * 64 + sni * 32 + c;
#pragma unroll
    for (int df = 0; df < 3; df++)
#pragma unroll
      for (int rg = 0; rg < 4; rg++) {
        int d0 = df * 32 + rg * 8 + hi * 4;
        if (d0 < HD) {
          uint2_t w;
          w[0] = cvtpk(accO[df][sni][rg * 4 + 0] * inv, accO[df][sni][rg * 4 + 1] * inv);
          w[1] = cvtpk(accO[df][sni][rg * 4 + 2] * inv, accO[df][sni][rg * 4 + 3] * inv);
          *(uint2_t*)&Oo[(size_t)token * DIMM + h * HD + d0] = w;
        }
      }
  }
}

// -------------------------------------------------------------------------------
extern "C" void kernel_launch(void* const* d_in, const int* in_sizes, int n_in,
                              void* d_out, int out_size, void* d_ws, size_t ws_size,
                              hipStream_t stream) {
  (void)in_sizes; (void)n_in; (void)out_size; (void)ws_size;
  const float* hs     = (const float*)d_in[0];
  const float* cosp   = (const float*)d_in[1];
  const float* sinp   = (const float*)d_in[2];
  const float* w_qkv  = (const float*)d_in[4];
  const float* b_qkv  = (const float*)d_in[5];
  const float* w_proj = (const float*)d_in[6];
  const float* b_proj = (const float*)d_in[7];
  float* out = (float*)d_out;

  char* ws = (char*)d_ws;
  bf16* hsb    = (bf16*)(ws + 0);          // 18874368
  bf16* wprojT = (bf16*)(ws + 26836992);   //  2654208
  bf16* qkv    = (bf16*)(ws + 29491200);   // 56623104
  bf16* Qp     = (bf16*)(ws + 86114304);   // 25165824
  bf16* Kp     = (bf16*)(ws + 111280128);  // 25165824
  bf16* Vt     = (bf16*)(ws + 136445952);  // 25165824
  bf16* ao     = (bf16*)(ws + 161611776);  // 18874368
  // wqkvT (padded to 3584 rows) aliases ao: its lifetime ends before attn.
  bf16* wqkvT  = (bf16*)(ws + 161611776);

  k_prep<<<5940, 256, 0, stream>>>(hs, hsb, w_qkv, wqkvT, w_proj, wprojT);
  k_gemmF<<<448, 512, 0, stream>>>(hsb, wqkvT, b_qkv, qkv, 8192, 3456, 1152, 14);
  k_ropev<<<4096, 256, 0, stream>>>(qkv, cosp, sinp, Qp, Kp, Vt);
  k_attn<<<512, 256, 0, stream>>>(Qp, Kp, Vt, ao);
  k_gemmP<128, 128, 4, 4, 256, true, 3><<<576, 256, 0, stream>>>(
      ao, wprojT, b_proj, (void*)out, 8192, 1152, 1152, 9);
}

// Round 16
// 247.468 us; speedup vs baseline: 1.0148x; 1.0148x over previous
//
#include <hip/hip_runtime.h>
#include <hip/hip_bf16.h>
#include <cstdint>
#include <cstddef>

typedef __bf16 bf16;
typedef __attribute__((ext_vector_type(4))) __bf16 bf16x4;
typedef __attribute__((ext_vector_type(8))) __bf16 bf16x8;
typedef __attribute__((ext_vector_type(4))) float f32x4;
typedef __attribute__((ext_vector_type(16))) float f32x16;
typedef __attribute__((ext_vector_type(4))) float floatx4;
typedef __attribute__((ext_vector_type(2))) unsigned uint2_t;
typedef __attribute__((ext_vector_type(4))) unsigned uint4_t;

// Problem constants
#define NTOK 8192
#define DIMM 1152
#define NH   16
#define HD   72
#define SEGS 4
#define SEGL 2048

__device__ __forceinline__ void gload16(const void* gsrc, void* ldst) {
  __builtin_amdgcn_global_load_lds(
      (const __attribute__((address_space(1))) void*)gsrc,
      (__attribute__((address_space(3))) void*)ldst,
      16, 0, 0);
}

// single-instruction pack: low16 = bf16(a), high16 = bf16(b)
__device__ __forceinline__ unsigned cvtpk(float a, float b) {
  unsigned r;
  asm volatile("v_cvt_pk_bf16_f32 %0, %1, %2" : "=v"(r) : "v"(a), "v"(b));
  return r;
}

// ---- fused prep: [0,4608) f32->bf16 cvt of hs; then two transposed weights ----
__global__ __launch_bounds__(256) void k_prep(const float* __restrict__ hs,
                                              bf16* __restrict__ hsb,
                                              const float* __restrict__ wq,
                                              bf16* __restrict__ wqT,
                                              const float* __restrict__ wp,
                                              bf16* __restrict__ wpT) {
  __shared__ bf16 tile[64][73];
  const int b = blockIdx.x, t = threadIdx.x;
  if (b < 4608) {
    int i = b * 256 + t;
    const floatx4* s = (const floatx4*)hs + (size_t)i * 2;
    floatx4 a = s[0], c = s[1];
    uint4_t o;
    o[0] = cvtpk(a.x, a.y);
    o[1] = cvtpk(a.z, a.w);
    o[2] = cvtpk(c.x, c.y);
    o[3] = cvtpk(c.z, c.w);
    *((uint4_t*)hsb + i) = o;
    return;
  }
  const float* src; bf16* dst; int R, C, bx, by;
  if (b < 4608 + 1008) {
    int idx = b - 4608;
    src = wq; dst = wqT; R = 1152; C = 3456; bx = idx % 56; by = idx / 56;
  } else {
    int idx = b - 5616;
    src = wp; dst = wpT; R = 1152; C = 1152; bx = idx % 18; by = idx / 18;
  }
  int bc = bx * 64, br = by * 64;
#pragma unroll
  for (int i = 0; i < 16; i++) {
    int idx = i * 256 + t;
    int r = idx >> 6, c = idx & 63;
    float v = (bc + c < C) ? src[(size_t)(br + r) * C + bc + c] : 0.f;
    tile[c][r] = (bf16)v;
  }
  __syncthreads();
#pragma unroll
  for (int i = 0; i < 16; i++) {
    int idx = i * 256 + t;
    int r = idx >> 6, c = idx & 63;
    dst[(size_t)(bc + r) * R + br + c] = tile[r][c];
  }
}

// ---- bf16 GEMM 256x256 (QKV): counted-vmcnt phase pipeline (round-5 proven) ---
template <bool OUT_F32>
__global__ __launch_bounds__(512, 2) void k_gemm8(const bf16* __restrict__ A,
                                                  const bf16* __restrict__ Bt,
                                                  const float* __restrict__ bias,
                                                  void* __restrict__ Cout,
                                                  int M, int Nreal, int K, int gx) {
  __shared__ bf16 sA[2][2][256 * 32];
  __shared__ bf16 sB[2][2][256 * 32];
  const int t = threadIdx.x, wave = t >> 6, lane = t & 63;
  const int lr = lane & 15, lg = lane >> 4;
  const int nwg = gridDim.x, bid = blockIdx.x;
  const int swz = (bid & 7) * (nwg >> 3) + (bid >> 3);
  const int bx = swz % gx, by = swz / gx;
  const int m0 = by * 256, n0 = bx * 256;
  const int wr = wave >> 2;
  const int wn = (wave & 3) * 64;
  const int NT = K >> 6;

  f32x4 acc[8][4];
#pragma unroll
  for (int i = 0; i < 8; i++)
#pragma unroll
    for (int j = 0; j < 4; j++)
#pragma unroll
      for (int q = 0; q < 4; q++) acc[i][j][q] = 0.f;

  const bf16* Ab = A + (size_t)m0 * K;
  const bf16* Bb = Bt + (size_t)n0 * K;
  const int glsw = ((t & 3) ^ ((t >> 3) & 3)) * 8;
  const bf16* Asrc0 = Ab + (size_t)(t >> 2) * K + glsw;
  const bf16* Asrc1 = Ab + (size_t)((t >> 2) + 128) * K + glsw;
  const bf16* Bsrc0 = Bb + (size_t)(t >> 2) * K + glsw;
  const bf16* Bsrc1 = Bb + (size_t)((t >> 2) + 128) * K + glsw;
  const int swz4 = (lr >> 1) & 3;
  const int aoff = (wr * 128 + lr) * 32 + ((lg ^ swz4) * 8);
  const int boff = (wn + lr) * 32 + ((lg ^ swz4) * 8);

#pragma unroll
  for (int kh = 0; kh < 2; ++kh) {
    const int k0 = kh * 32;
    char* dA = (char*)&sA[0][kh][0] + wave * 1024;
    char* dB = (char*)&sB[0][kh][0] + wave * 1024;
    gload16(Asrc0 + k0, dA);
    gload16(Bsrc0 + k0, dB);
    gload16(Asrc1 + k0, dA + 8192);
    gload16(Bsrc1 + k0, dB + 8192);
  }

  for (int kt = 0; kt < NT; ++kt) {
    const int buf = kt & 1;
    const bool more = (kt + 1 < NT);
#pragma unroll
    for (int kh = 0; kh < 2; ++kh) {
      if (!more && kh == 1) {
        asm volatile("s_waitcnt vmcnt(0)" ::: "memory");
      } else {
        asm volatile("s_waitcnt vmcnt(4)" ::: "memory");
      }
      __builtin_amdgcn_s_barrier();
      __builtin_amdgcn_sched_barrier(0);
      const bf16* As = &sA[buf][kh][0];
      const bf16* Bs = &sB[buf][kh][0];
      bf16x8 av[8], bv[4];
#pragma unroll
      for (int mi = 0; mi < 8; mi++)
        av[mi] = *(const bf16x8*)&As[aoff + mi * 512];
#pragma unroll
      for (int ni = 0; ni < 4; ni++)
        bv[ni] = *(const bf16x8*)&Bs[boff + ni * 512];
      if (more) {
        const int k0 = (kt + 1) * 64 + kh * 32;
        char* dA = (char*)&sA[buf ^ 1][kh][0] + wave * 1024;
        char* dB = (char*)&sB[buf ^ 1][kh][0] + wave * 1024;
        gload16(Asrc0 + k0, dA);
        gload16(Bsrc0 + k0, dB);
        gload16(Asrc1 + k0, dA + 8192);
        gload16(Bsrc1 + k0, dB + 8192);
      }
      __builtin_amdgcn_s_setprio(1);
#pragma unroll
      for (int mi = 0; mi < 8; mi++)
#pragma unroll
        for (int ni = 0; ni < 4; ni++)
          acc[mi][ni] = __builtin_amdgcn_mfma_f32_16x16x32_bf16(av[mi], bv[ni], acc[mi][ni], 0, 0, 0);
      __builtin_amdgcn_s_setprio(0);
    }
  }

#pragma unroll
  for (int mi = 0; mi < 8; ++mi)
#pragma unroll
    for (int ni = 0; ni < 4; ++ni) {
      int col = n0 + wn + ni * 16 + lr;
      if (col < Nreal) {
        float bc_ = bias[col];
#pragma unroll
        for (int j = 0; j < 4; j++) {
          int row = m0 + wr * 128 + mi * 16 + lg * 4 + j;
          float v = acc[mi][ni][j] + bc_;
          if (OUT_F32)
            ((float*)Cout)[(size_t)row * Nreal + col] = v;
          else
            ((bf16*)Cout)[(size_t)row * Nreal + col] = (bf16)v;
        }
      }
    }
}

// ---- pipelined bf16 GEMM (proj): 3-slot LDS ring, one barrier per 32-K step ---
template <int BM, int BN, int MI, int NI, int THREADS, bool OUT_F32>
__global__ __launch_bounds__(THREADS, 3) void k_gemmP(const bf16* __restrict__ A,
                                                      const bf16* __restrict__ Bt,
                                                      const float* __restrict__ bias,
                                                      void* __restrict__ Cout,
                                                      int M, int Nreal, int K, int gx) {
  __shared__ bf16 sA[3][BM * 32];
  __shared__ bf16 sB[3][BN * 32];
  constexpr int WN = BN / (NI * 16);
  constexpr int nA = (BM * 4) / THREADS;
  constexpr int nB = (BN * 4) / THREADS;
  constexpr int NLD = nA + nB;
  static_assert(NLD == 3 || NLD == 4, "vmcnt literal");
  const int t = threadIdx.x, wave = t >> 6, lane = t & 63;
  const int lr = lane & 15, lg = lane >> 4;
  const int nwg = gridDim.x, bid = blockIdx.x;
  const int swz = (bid & 7) * (nwg >> 3) + (bid >> 3);
  const int bx = swz % gx, by = swz / gx;
  const int m0 = by * BM, n0 = bx * BN;
  const int wr = wave / WN, wc = wave % WN;
  const int NS = K >> 5;

  f32x4 acc[MI][NI];
#pragma unroll
  for (int i = 0; i < MI; i++)
#pragma unroll
    for (int j = 0; j < NI; j++)
#pragma unroll
      for (int q = 0; q < 4; q++) acc[i][j][q] = 0.f;

  const bf16* Ab = A + (size_t)m0 * K;
  const bf16* Bb = Bt + (size_t)n0 * K;
  const int glsw = ((t & 3) ^ ((t >> 3) & 3)) * 8;
  const int rbase = t >> 2;

  auto STAGE = [&](int slot, int k0) {
#pragma unroll
    for (int p = 0; p < nA; ++p)
      gload16(Ab + (size_t)(rbase + p * (THREADS / 4)) * K + k0 + glsw,
              (char*)&sA[slot][0] + p * (THREADS * 16) + wave * 1024);
#pragma unroll
    for (int p = 0; p < nB; ++p)
      gload16(Bb + (size_t)(rbase + p * (THREADS / 4)) * K + k0 + glsw,
              (char*)&sB[slot][0] + p * (THREADS * 16) + wave * 1024);
  };

  const int swz4 = (lr >> 1) & 3;
  const int aoff = (wr * MI * 16 + lr) * 32 + ((lg ^ swz4) * 8);
  const int boff = (wc * NI * 16 + lr) * 32 + ((lg ^ swz4) * 8);

  STAGE(0, 0);
  STAGE(1, 32);

  int slot = 0;
  for (int j = 0; j < NS; ++j) {
    if (j == NS - 1) {
      asm volatile("s_waitcnt vmcnt(0)" ::: "memory");
    } else if constexpr (NLD == 3) {
      asm volatile("s_waitcnt vmcnt(3)" ::: "memory");
    } else {
      asm volatile("s_waitcnt vmcnt(4)" ::: "memory");
    }
    __builtin_amdgcn_s_barrier();
    __builtin_amdgcn_sched_barrier(0);
    bf16x8 av[MI], bv[NI];
#pragma unroll
    for (int mi = 0; mi < MI; mi++)
      av[mi] = *(const bf16x8*)&sA[slot][aoff + mi * 512];
#pragma unroll
    for (int ni = 0; ni < NI; ni++)
      bv[ni] = *(const bf16x8*)&sB[slot][boff + ni * 512];
    asm volatile("s_waitcnt lgkmcnt(0)" ::: "memory");
    __builtin_amdgcn_sched_barrier(0);
    if (j + 2 < NS) {
      int s2 = slot + 2; if (s2 >= 3) s2 -= 3;
      STAGE(s2, (j + 2) * 32);
    }
    __builtin_amdgcn_s_setprio(1);
#pragma unroll
    for (int mi = 0; mi < MI; mi++)
#pragma unroll
      for (int ni = 0; ni < NI; ni++)
        acc[mi][ni] = __builtin_amdgcn_mfma_f32_16x16x32_bf16(av[mi], bv[ni], acc[mi][ni], 0, 0, 0);
    __builtin_amdgcn_s_setprio(0);
    if (++slot == 3) slot = 0;
  }

#pragma unroll
  for (int mi = 0; mi < MI; ++mi)
#pragma unroll
    for (int ni = 0; ni < NI; ++ni) {
      int col = n0 + wc * NI * 16 + ni * 16 + lr;
      if (col < Nreal) {
        float bc_ = bias[col];
#pragma unroll
        for (int j = 0; j < 4; j++) {
          int row = m0 + wr * MI * 16 + mi * 16 + lg * 4 + j;
          float v = acc[mi][ni][j] + bc_;
          if (OUT_F32)
            ((float*)Cout)[(size_t)row * Nreal + col] = v;
          else
            ((bf16*)Cout)[(size_t)row * Nreal + col] = (bf16)v;
        }
      }
    }
}

// ---- fused RoPE(vectorized) + V repack --------------------------------------
// bid < 2048: rope for 4 tokens -> Qp/Kp[s][h][3][2048][32], Q pre-scaled by
// log2(e)/sqrt(72). bid >= 2048: V transpose -> Vt[s][h][96][2048] w/ ones row.
__global__ __launch_bounds__(256) void k_ropev(const bf16* __restrict__ qkv,
                                               const float* __restrict__ cs,
                                               const float* __restrict__ sn,
                                               bf16* __restrict__ Qp,
                                               bf16* __restrict__ Kp,
                                               bf16* __restrict__ Vt) {
  __shared__ bf16 tl[64][80];
  const int bid = blockIdx.x, t = threadIdx.x;
  if (bid < 2048) {
    const float QS = 0.17002323f;  // log2(e)/sqrt(72)
    const int n0 = bid * 4;
#pragma unroll
    for (int it = 0; it < 6; ++it) {
      int idx = it * 256 + t;
      int tok = idx / 384;
      int r = idx - tok * 384;
      int which = r / 192;
      int r2 = r - which * 192;
      int h = r2 / 12;
      int d0 = (r2 - h * 12) * 8;
      int n = n0 + tok;
      bf16* dst = which ? Kp : Qp;
      size_t ob = ((((size_t)((n >> 11) * NH + h)) * 3 + (d0 >> 5)) * SEGL +
                   (n & 2047)) * 32 + (d0 & 31);
      if (d0 >= HD) {                     // pad region d = 72..95
        uint4_t z = {0u, 0u, 0u, 0u};
        *(uint4_t*)&dst[ob] = z;
        continue;
      }
      const bf16* rowp = qkv + (size_t)n * (3 * DIMM) + which * DIMM + h * HD;
      bf16x8 xv = *(const bf16x8*)&rowp[d0];
      float ov[8];
      if (d0 == 32) {                     // d 32..35: -in[d+36]; 36..39: in[d-36]
        bf16x4 a = *(const bf16x4*)&rowp[68];
        bf16x4 b = *(const bf16x4*)&rowp[0];
#pragma unroll
        for (int j = 0; j < 4; j++) { ov[j] = -(float)a[j]; ov[j + 4] = (float)b[j]; }
      } else if (d0 < 32) {               // all d < 36: -in[d+36]
        bf16x4 a = *(const bf16x4*)&rowp[d0 + 36];
        bf16x4 b = *(const bf16x4*)&rowp[d0 + 40];
#pragma unroll
        for (int j = 0; j < 4; j++) { ov[j] = -(float)a[j]; ov[j + 4] = -(float)b[j]; }
      } else {                            // all d >= 36: in[d-36]
        bf16x4 a = *(const bf16x4*)&rowp[d0 - 36];
        bf16x4 b = *(const bf16x4*)&rowp[d0 - 32];
#pragma unroll
        for (int j = 0; j < 4; j++) { ov[j] = (float)a[j]; ov[j + 4] = (float)b[j]; }
      }
      const float* cr = cs + (size_t)n * HD + d0;
      const float* sr = sn + (size_t)n * HD + d0;
      floatx4 c0 = *(const floatx4*)cr, c1 = *(const floatx4*)(cr + 4);
      floatx4 s0 = *(const floatx4*)sr, s1 = *(const floatx4*)(sr + 4);
      float vv[8];
#pragma unroll
      for (int j = 0; j < 4; j++) {
        vv[j] = (float)xv[j] * c0[j] + ov[j] * s0[j];
        vv[j + 4] = (float)xv[j + 4] * c1[j] + ov[j + 4] * s1[j];
      }
      if (!which) {
#pragma unroll
        for (int j = 0; j < 8; j++) vv[j] *= QS;
      }
      uint4_t w;
      w[0] = cvtpk(vv[0], vv[1]);
      w[1] = cvtpk(vv[2], vv[3]);
      w[2] = cvtpk(vv[4], vv[5]);
      w[3] = cvtpk(vv[6], vv[7]);
      *(uint4_t*)&dst[ob] = w;
    }
  } else {
    int idx2 = bid - 2048;
    int s = idx2 >> 9, h = (idx2 >> 5) & 15, l0 = (idx2 & 31) * 64;
    for (int idx = t; idx < 64 * HD; idx += 256) {
      int l = idx / HD, d = idx - l * HD;
      tl[l][d] = qkv[(size_t)(s * SEGL + l0 + l) * (3 * DIMM) + 2 * DIMM + h * HD + d];
    }
    __syncthreads();
    for (int idx = t; idx < 96 * 64; idx += 256) {
      int d = idx >> 6, l = idx & 63;
      bf16 v = (d < HD) ? tl[l][d] : ((d == HD) ? (bf16)1.f : (bf16)0.f);
      Vt[((size_t)(s * NH + h) * 96 + d) * SEGL + l0 + l] = v;
    }
  }
}

// ---------------- flash attention (round-8 structure) --------------------------
__global__ __launch_bounds__(256, 2) void k_attn(const bf16* __restrict__ Qg,
                                                 const bf16* __restrict__ Kg,
                                                 const bf16* __restrict__ Vg,
                                                 bf16* __restrict__ Oo) {
  __shared__ bf16 sK[2][3 * 64 * 32];   // 2 x 12 KB
  __shared__ bf16 sV[2][96 * 64];       // 2 x 12 KB
  const int t = threadIdx.x, wave = t >> 6, lane = t & 63;
  const int c = lane & 31, hi = lane >> 5;
  const int bid = blockIdx.x;
  const int g = ((bid >> 6) << 3) | (bid & 7);   // group 0..63 (xcd = g&7)
  const int qt = (bid >> 3) & 7;
  const int s = g >> 4, h = g & 15, q0 = qt * 256;
  const bf16* Qb = Qg + (size_t)(s * NH + h) * 3 * SEGL * 32;
  const bf16* Kb = Kg + (size_t)(s * NH + h) * 3 * SEGL * 32;
  const bf16* Vb = Vg + (size_t)(s * NH + h) * 96 * SEGL;

  const bf16* kq[3];
  const bf16* vq[3];
#pragma unroll
  for (int i = 0; i < 3; i++) {
    int ch = wave * 3 + i;
    int kk = ch >> 2;
    int r = (ch & 3) * 16 + (lane >> 2);
    int gg = (lane & 3) ^ ((r >> 1) & 3);
    kq[i] = Kb + (size_t)kk * (SEGL * 32) + (size_t)r * 32 + gg * 8;
    int rv = ch * 8 + (lane >> 3);
    int gv = (lane & 7) ^ (rv & 7);
    vq[i] = Vb + (size_t)rv * SEGL + gv * 8;
  }

  bf16x8 Qf[2][5];
#pragma unroll
  for (int sni = 0; sni < 2; sni++)
#pragma unroll
    for (int kk = 0; kk < 5; kk++) {
      int qr = q0 + wave * 64 + sni * 32 + c;
      Qf[sni][kk] = *(const bf16x8*)&Qb[(size_t)(kk >> 1) * (SEGL * 32) +
                                        (size_t)qr * 32 + ((kk & 1) * 2 + hi) * 8];
    }

#pragma unroll
  for (int i = 0; i < 3; i++) {
    gload16(kq[i], (char*)sK[0] + (wave * 3 + i) * 1024);
    gload16(vq[i], (char*)sV[0] + (wave * 3 + i) * 1024);
    kq[i] += 2048;
    vq[i] += 64;
  }
  __syncthreads();

  f32x16 accO[3][2];
#pragma unroll
  for (int df = 0; df < 3; df++)
#pragma unroll
    for (int sni = 0; sni < 2; sni++)
#pragma unroll
      for (int r = 0; r < 16; r++) accO[df][sni][r] = 0.f;
  f32x16 ZC;
#pragma unroll
  for (int r = 0; r < 16; r++) ZC[r] = 0.f;

  int cur = 0;
  for (int tile = 0; tile < 32; ++tile) {
    if (tile + 1 < 32) {
#pragma unroll
      for (int i = 0; i < 3; i++) {
        gload16(kq[i], (char*)sK[cur ^ 1] + (wave * 3 + i) * 1024);
        gload16(vq[i], (char*)sV[cur ^ 1] + (wave * 3 + i) * 1024);
        kq[i] += 2048;
        vq[i] += 64;
      }
    }

    // ===== S^T = K · Q =====
    f32x16 S[2][2];
    __builtin_amdgcn_s_setprio(1);
#pragma unroll
    for (int kk = 0; kk < 5; kk++) {
      bf16x8 Kf[2];
#pragma unroll
      for (int smi = 0; smi < 2; smi++) {
        int kr = smi * 32 + c;
        int gg = (((kk & 1) * 2 + hi) ^ ((kr >> 1) & 3));
        Kf[smi] = *(const bf16x8*)&sK[cur][(kk >> 1) * 2048 + kr * 32 + gg * 8];
      }
#pragma unroll
      for (int smi = 0; smi < 2; smi++)
#pragma unroll
        for (int sni = 0; sni < 2; sni++)
          S[smi][sni] = __builtin_amdgcn_mfma_f32_32x32x16_bf16(
              Kf[smi], Qf[sni][kk], kk ? S[smi][sni] : ZC, 0, 0, 0);
    }
    __builtin_amdgcn_s_setprio(0);

    // ===== O^T += V^T · P^T =====
    __builtin_amdgcn_s_setprio(1);
#pragma unroll
    for (int kk = 0; kk < 4; kk++) {
      bf16x8 Vf[3];
#pragma unroll
      for (int df = 0; df < 3; df++) {
        int dr = df * 32 + c;
        int gg = ((kk * 2 + hi) ^ (dr & 7));
        Vf[df] = *(const bf16x8*)&sV[cur][dr * 64 + gg * 8];
      }
#pragma unroll
      for (int sni = 0; sni < 2; sni++) {
        const int smi = kk >> 1;
        const int base = (kk & 1) * 8;
        unsigned u0 = cvtpk(__builtin_amdgcn_exp2f(S[smi][sni][base + 0]),
                            __builtin_amdgcn_exp2f(S[smi][sni][base + 1]));
        unsigned u1 = cvtpk(__builtin_amdgcn_exp2f(S[smi][sni][base + 2]),
                            __builtin_amdgcn_exp2f(S[smi][sni][base + 3]));
        unsigned u2 = cvtpk(__builtin_amdgcn_exp2f(S[smi][sni][base + 4]),
                            __builtin_amdgcn_exp2f(S[smi][sni][base + 5]));
        unsigned u3 = cvtpk(__builtin_amdgcn_exp2f(S[smi][sni][base + 6]),
                            __builtin_amdgcn_exp2f(S[smi][sni][base + 7]));
        asm volatile("v_permlane32_swap_b32 %0, %1" : "+v"(u0), "+v"(u2));
        asm volatile("v_permlane32_swap_b32 %0, %1" : "+v"(u1), "+v"(u3));
        union { bf16x8 v; unsigned u[4]; } pb;
        pb.u[0] = u0; pb.u[1] = u1; pb.u[2] = u2; pb.u[3] = u3;
#pragma unroll
        for (int df = 0; df < 3; df++)
          accO[df][sni] = __builtin_amdgcn_mfma_f32_32x32x16_bf16(Vf[df], pb.v, accO[df][sni], 0, 0, 0);
      }
    }
    __builtin_amdgcn_s_setprio(0);

    __syncthreads();
    cur ^= 1;
  }

  // ===== write O (token-major), 8 B packed stores =====
#pragma unroll
  for (int sni = 0; sni < 2; sni++) {
    float lown = accO[2][sni][4];
    float lv = lown + __shfl_xor(lown, 32, 64);
    float inv = 1.f / lv;
    int token = s * SEGL + q0 + wave * 64 + sni * 32 + c;
#pragma unroll
    for (int df = 0; df < 3; df++)
#pragma unroll
      for (int rg = 0; rg < 4; rg++) {
        int d0 = df * 32 + rg * 8 + hi * 4;
        if (d0 < HD) {
          uint2_t w;
          w[0] = cvtpk(accO[df][sni][rg * 4 + 0] * inv, accO[df][sni][rg * 4 + 1] * inv);
          w[1] = cvtpk(accO[df][sni][rg * 4 + 2] * inv, accO[df][sni][rg * 4 + 3] * inv);
          *(uint2_t*)&Oo[(size_t)token * DIMM + h * HD + d0] = w;
        }
      }
  }
}

// -------------------------------------------------------------------------------
extern "C" void kernel_launch(void* const* d_in, const int* in_sizes, int n_in,
                              void* d_out, int out_size, void* d_ws, size_t ws_size,
                              hipStream_t stream) {
  (void)in_sizes; (void)n_in; (void)out_size; (void)ws_size;
  const float* hs     = (const float*)d_in[0];
  const float* cosp   = (const float*)d_in[1];
  const float* sinp   = (const float*)d_in[2];
  const float* w_qkv  = (const float*)d_in[4];
  const float* b_qkv  = (const float*)d_in[5];
  const float* w_proj = (const float*)d_in[6];
  const float* b_proj = (const float*)d_in[7];
  float* out = (float*)d_out;

  char* ws = (char*)d_ws;
  bf16* hsb    = (bf16*)(ws + 0);          // 18874368
  bf16* wprojT = (bf16*)(ws + 26836992);   //  2654208
  bf16* qkv    = (bf16*)(ws + 29491200);   // 56623104
  bf16* Qp     = (bf16*)(ws + 86114304);   // 25165824
  bf16* Kp     = (bf16*)(ws + 111280128);  // 25165824
  bf16* Vt     = (bf16*)(ws + 136445952);  // 25165824
  bf16* ao     = (bf16*)(ws + 161611776);  // 18874368
  // wqkvT (padded to 3584 rows) aliases ao: its lifetime ends before attn.
  bf16* wqkvT  = (bf16*)(ws + 161611776);

  k_prep<<<5940, 256, 0, stream>>>(hs, hsb, w_qkv, wqkvT, w_proj, wprojT);
  k_gemm8<false><<<448, 512, 0, stream>>>(hsb, wqkvT, b_qkv, (void*)qkv, 8192, 3456, 1152, 14);
  k_ropev<<<4096, 256, 0, stream>>>(qkv, cosp, sinp, Qp, Kp, Vt);
  k_attn<<<512, 256, 0, stream>>>(Qp, Kp, Vt, ao);
  k_gemmP<128, 128, 4, 4, 256, true><<<576, 256, 0, stream>>>(
      ao, wprojT, b_proj, (void*)out, 8192, 1152, 1152, 9);
}

// Round 17
// 242.359 us; speedup vs baseline: 1.0362x; 1.0211x over previous
//
#include <hip/hip_runtime.h>
#include <hip/hip_bf16.h>
#include <cstdint>
#include <cstddef>

typedef __bf16 bf16;
typedef __attribute__((ext_vector_type(4))) __bf16 bf16x4;
typedef __attribute__((ext_vector_type(8))) __bf16 bf16x8;
typedef __attribute__((ext_vector_type(4))) float f32x4;
typedef __attribute__((ext_vector_type(16))) float f32x16;
typedef __attribute__((ext_vector_type(4))) float floatx4;
typedef __attribute__((ext_vector_type(2))) unsigned uint2_t;
typedef __attribute__((ext_vector_type(4))) unsigned uint4_t;

// Problem constants
#define NTOK 8192
#define DIMM 1152
#define NH   16
#define HD   72
#define SEGS 4
#define SEGL 2048

__device__ __forceinline__ void gload16(const void* gsrc, void* ldst) {
  __builtin_amdgcn_global_load_lds(
      (const __attribute__((address_space(1))) void*)gsrc,
      (__attribute__((address_space(3))) void*)ldst,
      16, 0, 0);
}

// single-instruction pack: low16 = bf16(a), high16 = bf16(b)
__device__ __forceinline__ unsigned cvtpk(float a, float b) {
  unsigned r;
  asm volatile("v_cvt_pk_bf16_f32 %0, %1, %2" : "=v"(r) : "v"(a), "v"(b));
  return r;
}

// ---- fused prep: [0,4608) f32->bf16 cvt of hs; then two transposed weights ----
__global__ __launch_bounds__(256) void k_prep(const float* __restrict__ hs,
                                              bf16* __restrict__ hsb,
                                              const float* __restrict__ wq,
                                              bf16* __restrict__ wqT,
                                              const float* __restrict__ wp,
                                              bf16* __restrict__ wpT) {
  __shared__ bf16 tile[64][73];
  const int b = blockIdx.x, t = threadIdx.x;
  if (b < 4608) {
    int i = b * 256 + t;
    const floatx4* s = (const floatx4*)hs + (size_t)i * 2;
    floatx4 a = s[0], c = s[1];
    uint4_t o;
    o[0] = cvtpk(a.x, a.y);
    o[1] = cvtpk(a.z, a.w);
    o[2] = cvtpk(c.x, c.y);
    o[3] = cvtpk(c.z, c.w);
    *((uint4_t*)hsb + i) = o;
    return;
  }
  const float* src; bf16* dst; int R, C, bx, by;
  if (b < 4608 + 1008) {
    int idx = b - 4608;
    src = wq; dst = wqT; R = 1152; C = 3456; bx = idx % 56; by = idx / 56;
  } else {
    int idx = b - 5616;
    src = wp; dst = wpT; R = 1152; C = 1152; bx = idx % 18; by = idx / 18;
  }
  int bc = bx * 64, br = by * 64;
#pragma unroll
  for (int i = 0; i < 16; i++) {
    int idx = i * 256 + t;
    int r = idx >> 6, c = idx & 63;
    float v = (bc + c < C) ? src[(size_t)(br + r) * C + bc + c] : 0.f;
    tile[c][r] = (bf16)v;
  }
  __syncthreads();
#pragma unroll
  for (int i = 0; i < 16; i++) {
    int idx = i * 256 + t;
    int r = idx >> 6, c = idx & 63;
    dst[(size_t)(bc + r) * R + br + c] = tile[r][c];
  }
}

// ---- bf16 GEMM 256x256 (QKV): counted-vmcnt phase pipeline (round-5 proven) ---
template <bool OUT_F32>
__global__ __launch_bounds__(512, 2) void k_gemm8(const bf16* __restrict__ A,
                                                  const bf16* __restrict__ Bt,
                                                  const float* __restrict__ bias,
                                                  void* __restrict__ Cout,
                                                  int M, int Nreal, int K, int gx) {
  __shared__ bf16 sA[2][2][256 * 32];
  __shared__ bf16 sB[2][2][256 * 32];
  const int t = threadIdx.x, wave = t >> 6, lane = t & 63;
  const int lr = lane & 15, lg = lane >> 4;
  const int nwg = gridDim.x, bid = blockIdx.x;
  const int swz = (bid & 7) * (nwg >> 3) + (bid >> 3);
  const int bx = swz % gx, by = swz / gx;
  const int m0 = by * 256, n0 = bx * 256;
  const int wr = wave >> 2;
  const int wn = (wave & 3) * 64;
  const int NT = K >> 6;

  f32x4 acc[8][4];
#pragma unroll
  for (int i = 0; i < 8; i++)
#pragma unroll
    for (int j = 0; j < 4; j++)
#pragma unroll
      for (int q = 0; q < 4; q++) acc[i][j][q] = 0.f;

  const bf16* Ab = A + (size_t)m0 * K;
  const bf16* Bb = Bt + (size_t)n0 * K;
  const int glsw = ((t & 3) ^ ((t >> 3) & 3)) * 8;
  const bf16* Asrc0 = Ab + (size_t)(t >> 2) * K + glsw;
  const bf16* Asrc1 = Ab + (size_t)((t >> 2) + 128) * K + glsw;
  const bf16* Bsrc0 = Bb + (size_t)(t >> 2) * K + glsw;
  const bf16* Bsrc1 = Bb + (size_t)((t >> 2) + 128) * K + glsw;
  const int swz4 = (lr >> 1) & 3;
  const int aoff = (wr * 128 + lr) * 32 + ((lg ^ swz4) * 8);
  const int boff = (wn + lr) * 32 + ((lg ^ swz4) * 8);

#pragma unroll
  for (int kh = 0; kh < 2; ++kh) {
    const int k0 = kh * 32;
    char* dA = (char*)&sA[0][kh][0] + wave * 1024;
    char* dB = (char*)&sB[0][kh][0] + wave * 1024;
    gload16(Asrc0 + k0, dA);
    gload16(Bsrc0 + k0, dB);
    gload16(Asrc1 + k0, dA + 8192);
    gload16(Bsrc1 + k0, dB + 8192);
  }

  for (int kt = 0; kt < NT; ++kt) {
    const int buf = kt & 1;
    const bool more = (kt + 1 < NT);
#pragma unroll
    for (int kh = 0; kh < 2; ++kh) {
      if (!more && kh == 1) {
        asm volatile("s_waitcnt vmcnt(0)" ::: "memory");
      } else {
        asm volatile("s_waitcnt vmcnt(4)" ::: "memory");
      }
      __builtin_amdgcn_s_barrier();
      __builtin_amdgcn_sched_barrier(0);
      const bf16* As = &sA[buf][kh][0];
      const bf16* Bs = &sB[buf][kh][0];
      bf16x8 av[8], bv[4];
#pragma unroll
      for (int mi = 0; mi < 8; mi++)
        av[mi] = *(const bf16x8*)&As[aoff + mi * 512];
#pragma unroll
      for (int ni = 0; ni < 4; ni++)
        bv[ni] = *(const bf16x8*)&Bs[boff + ni * 512];
      if (more) {
        const int k0 = (kt + 1) * 64 + kh * 32;
        char* dA = (char*)&sA[buf ^ 1][kh][0] + wave * 1024;
        char* dB = (char*)&sB[buf ^ 1][kh][0] + wave * 1024;
        gload16(Asrc0 + k0, dA);
        gload16(Bsrc0 + k0, dB);
        gload16(Asrc1 + k0, dA + 8192);
        gload16(Bsrc1 + k0, dB + 8192);
      }
      __builtin_amdgcn_s_setprio(1);
#pragma unroll
      for (int mi = 0; mi < 8; mi++)
#pragma unroll
        for (int ni = 0; ni < 4; ni++)
          acc[mi][ni] = __builtin_amdgcn_mfma_f32_16x16x32_bf16(av[mi], bv[ni], acc[mi][ni], 0, 0, 0);
      __builtin_amdgcn_s_setprio(0);
    }
  }

#pragma unroll
  for (int mi = 0; mi < 8; ++mi)
#pragma unroll
    for (int ni = 0; ni < 4; ++ni) {
      int col = n0 + wn + ni * 16 + lr;
      if (col < Nreal) {
        float bc_ = bias[col];
#pragma unroll
        for (int j = 0; j < 4; j++) {
          int row = m0 + wr * 128 + mi * 16 + lg * 4 + j;
          float v = acc[mi][ni][j] + bc_;
          if (OUT_F32)
            ((float*)Cout)[(size_t)row * Nreal + col] = v;
          else
            ((bf16*)Cout)[(size_t)row * Nreal + col] = (bf16)v;
        }
      }
    }
}

// ---- pipelined bf16 GEMM (proj): 3-slot LDS ring, one barrier per 32-K step ---
template <int BM, int BN, int MI, int NI, int THREADS, bool OUT_F32>
__global__ __launch_bounds__(THREADS, 3) void k_gemmP(const bf16* __restrict__ A,
                                                      const bf16* __restrict__ Bt,
                                                      const float* __restrict__ bias,
                                                      void* __restrict__ Cout,
                                                      int M, int Nreal, int K, int gx) {
  __shared__ bf16 sA[3][BM * 32];
  __shared__ bf16 sB[3][BN * 32];
  constexpr int WN = BN / (NI * 16);
  constexpr int nA = (BM * 4) / THREADS;
  constexpr int nB = (BN * 4) / THREADS;
  constexpr int NLD = nA + nB;
  static_assert(NLD == 3 || NLD == 4, "vmcnt literal");
  const int t = threadIdx.x, wave = t >> 6, lane = t & 63;
  const int lr = lane & 15, lg = lane >> 4;
  const int nwg = gridDim.x, bid = blockIdx.x;
  const int swz = (bid & 7) * (nwg >> 3) + (bid >> 3);
  const int bx = swz % gx, by = swz / gx;
  const int m0 = by * BM, n0 = bx * BN;
  const int wr = wave / WN, wc = wave % WN;
  const int NS = K >> 5;

  f32x4 acc[MI][NI];
#pragma unroll
  for (int i = 0; i < MI; i++)
#pragma unroll
    for (int j = 0; j < NI; j++)
#pragma unroll
      for (int q = 0; q < 4; q++) acc[i][j][q] = 0.f;

  const bf16* Ab = A + (size_t)m0 * K;
  const bf16* Bb = Bt + (size_t)n0 * K;
  const int glsw = ((t & 3) ^ ((t >> 3) & 3)) * 8;
  const int rbase = t >> 2;

  auto STAGE = [&](int slot, int k0) {
#pragma unroll
    for (int p = 0; p < nA; ++p)
      gload16(Ab + (size_t)(rbase + p * (THREADS / 4)) * K + k0 + glsw,
              (char*)&sA[slot][0] + p * (THREADS * 16) + wave * 1024);
#pragma unroll
    for (int p = 0; p < nB; ++p)
      gload16(Bb + (size_t)(rbase + p * (THREADS / 4)) * K + k0 + glsw,
              (char*)&sB[slot][0] + p * (THREADS * 16) + wave * 1024);
  };

  const int swz4 = (lr >> 1) & 3;
  const int aoff = (wr * MI * 16 + lr) * 32 + ((lg ^ swz4) * 8);
  const int boff = (wc * NI * 16 + lr) * 32 + ((lg ^ swz4) * 8);

  STAGE(0, 0);
  STAGE(1, 32);

  int slot = 0;
  for (int j = 0; j < NS; ++j) {
    if (j == NS - 1) {
      asm volatile("s_waitcnt vmcnt(0)" ::: "memory");
    } else if constexpr (NLD == 3) {
      asm volatile("s_waitcnt vmcnt(3)" ::: "memory");
    } else {
      asm volatile("s_waitcnt vmcnt(4)" ::: "memory");
    }
    __builtin_amdgcn_s_barrier();
    __builtin_amdgcn_sched_barrier(0);
    bf16x8 av[MI], bv[NI];
#pragma unroll
    for (int mi = 0; mi < MI; mi++)
      av[mi] = *(const bf16x8*)&sA[slot][aoff + mi * 512];
#pragma unroll
    for (int ni = 0; ni < NI; ni++)
      bv[ni] = *(const bf16x8*)&sB[slot][boff + ni * 512];
    asm volatile("s_waitcnt lgkmcnt(0)" ::: "memory");
    __builtin_amdgcn_sched_barrier(0);
    if (j + 2 < NS) {
      int s2 = slot + 2; if (s2 >= 3) s2 -= 3;
      STAGE(s2, (j + 2) * 32);
    }
    __builtin_amdgcn_s_setprio(1);
#pragma unroll
    for (int mi = 0; mi < MI; mi++)
#pragma unroll
      for (int ni = 0; ni < NI; ni++)
        acc[mi][ni] = __builtin_amdgcn_mfma_f32_16x16x32_bf16(av[mi], bv[ni], acc[mi][ni], 0, 0, 0);
    __builtin_amdgcn_s_setprio(0);
    if (++slot == 3) slot = 0;
  }

#pragma unroll
  for (int mi = 0; mi < MI; ++mi)
#pragma unroll
    for (int ni = 0; ni < NI; ++ni) {
      int col = n0 + wc * NI * 16 + ni * 16 + lr;
      if (col < Nreal) {
        float bc_ = bias[col];
#pragma unroll
        for (int j = 0; j < 4; j++) {
          int row = m0 + wr * MI * 16 + mi * 16 + lg * 4 + j;
          float v = acc[mi][ni][j] + bc_;
          if (OUT_F32)
            ((float*)Cout)[(size_t)row * Nreal + col] = v;
          else
            ((bf16*)Cout)[(size_t)row * Nreal + col] = (bf16)v;
        }
      }
    }
}

// ---- fused RoPE(vectorized) + V repack --------------------------------------
// bid < 2048: rope for 4 tokens -> Qp/Kp[s][h][3][2048][32], Q pre-scaled by
// log2(e)/sqrt(72). bid >= 2048: V transpose -> Vt[s][h][96][2048] w/ ones row.
__global__ __launch_bounds__(256) void k_ropev(const bf16* __restrict__ qkv,
                                               const float* __restrict__ cs,
                                               const float* __restrict__ sn,
                                               bf16* __restrict__ Qp,
                                               bf16* __restrict__ Kp,
                                               bf16* __restrict__ Vt) {
  __shared__ bf16 tl[64][80];
  const int bid = blockIdx.x, t = threadIdx.x;
  if (bid < 2048) {
    const float QS = 0.17002323f;  // log2(e)/sqrt(72)
    const int n0 = bid * 4;
#pragma unroll
    for (int it = 0; it < 6; ++it) {
      int idx = it * 256 + t;
      int tok = idx / 384;
      int r = idx - tok * 384;
      int which = r / 192;
      int r2 = r - which * 192;
      int h = r2 / 12;
      int d0 = (r2 - h * 12) * 8;
      int n = n0 + tok;
      bf16* dst = which ? Kp : Qp;
      size_t ob = ((((size_t)((n >> 11) * NH + h)) * 3 + (d0 >> 5)) * SEGL +
                   (n & 2047)) * 32 + (d0 & 31);
      if (d0 >= HD) {                     // pad region d = 72..95
        uint4_t z = {0u, 0u, 0u, 0u};
        *(uint4_t*)&dst[ob] = z;
        continue;
      }
      const bf16* rowp = qkv + (size_t)n * (3 * DIMM) + which * DIMM + h * HD;
      bf16x8 xv = *(const bf16x8*)&rowp[d0];
      float ov[8];
      if (d0 == 32) {                     // d 32..35: -in[d+36]; 36..39: in[d-36]
        bf16x4 a = *(const bf16x4*)&rowp[68];
        bf16x4 b = *(const bf16x4*)&rowp[0];
#pragma unroll
        for (int j = 0; j < 4; j++) { ov[j] = -(float)a[j]; ov[j + 4] = (float)b[j]; }
      } else if (d0 < 32) {               // all d < 36: -in[d+36]
        bf16x4 a = *(const bf16x4*)&rowp[d0 + 36];
        bf16x4 b = *(const bf16x4*)&rowp[d0 + 40];
#pragma unroll
        for (int j = 0; j < 4; j++) { ov[j] = -(float)a[j]; ov[j + 4] = -(float)b[j]; }
      } else {                            // all d >= 36: in[d-36]
        bf16x4 a = *(const bf16x4*)&rowp[d0 - 36];
        bf16x4 b = *(const bf16x4*)&rowp[d0 - 32];
#pragma unroll
        for (int j = 0; j < 4; j++) { ov[j] = (float)a[j]; ov[j + 4] = (float)b[j]; }
      }
      const float* cr = cs + (size_t)n * HD + d0;
      const float* sr = sn + (size_t)n * HD + d0;
      floatx4 c0 = *(const floatx4*)cr, c1 = *(const floatx4*)(cr + 4);
      floatx4 s0 = *(const floatx4*)sr, s1 = *(const floatx4*)(sr + 4);
      float vv[8];
#pragma unroll
      for (int j = 0; j < 4; j++) {
        vv[j] = (float)xv[j] * c0[j] + ov[j] * s0[j];
        vv[j + 4] = (float)xv[j + 4] * c1[j] + ov[j + 4] * s1[j];
      }
      if (!which) {
#pragma unroll
        for (int j = 0; j < 8; j++) vv[j] *= QS;
      }
      uint4_t w;
      w[0] = cvtpk(vv[0], vv[1]);
      w[1] = cvtpk(vv[2], vv[3]);
      w[2] = cvtpk(vv[4], vv[5]);
      w[3] = cvtpk(vv[6], vv[7]);
      *(uint4_t*)&dst[ob] = w;
    }
  } else {
    int idx2 = bid - 2048;
    int s = idx2 >> 9, h = (idx2 >> 5) & 15, l0 = (idx2 & 31) * 64;
    for (int idx = t; idx < 64 * HD; idx += 256) {
      int l = idx / HD, d = idx - l * HD;
      tl[l][d] = qkv[(size_t)(s * SEGL + l0 + l) * (3 * DIMM) + 2 * DIMM + h * HD + d];
    }
    __syncthreads();
    for (int idx = t; idx < 96 * 64; idx += 256) {
      int d = idx >> 6, l = idx & 63;
      bf16 v = (d < HD) ? tl[l][d] : ((d == HD) ? (bf16)1.f : (bf16)0.f);
      Vt[((size_t)(s * NH + h) * 96 + d) * SEGL + l0 + l] = v;
    }
  }
}

// ---------------- flash attention (round-8 structure) --------------------------
__global__ __launch_bounds__(256, 2) void k_attn(const bf16* __restrict__ Qg,
                                                 const bf16* __restrict__ Kg,
                                                 const bf16* __restrict__ Vg,
                                                 bf16* __restrict__ Oo) {
  __shared__ bf16 sK[2][3 * 64 * 32];   // 2 x 12 KB
  __shared__ bf16 sV[2][96 * 64];       // 2 x 12 KB
  const int t = threadIdx.x, wave = t >> 6, lane = t & 63;
  const int c = lane & 31, hi = lane >> 5;
  const int bid = blockIdx.x;
  const int g = ((bid >> 6) << 3) | (bid & 7);   // group 0..63 (xcd = g&7)
  const int qt = (bid >> 3) & 7;
  const int s = g >> 4, h = g & 15, q0 = qt * 256;
  const bf16* Qb = Qg + (size_t)(s * NH + h) * 3 * SEGL * 32;
  const bf16* Kb = Kg + (size_t)(s * NH + h) * 3 * SEGL * 32;
  const bf16* Vb = Vg + (size_t)(s * NH + h) * 96 * SEGL;

  const bf16* kq[3];
  const bf16* vq[3];
#pragma unroll
  for (int i = 0; i < 3; i++) {
    int ch = wave * 3 + i;
    int kk = ch >> 2;
    int r = (ch & 3) * 16 + (lane >> 2);
    int gg = (lane & 3) ^ ((r >> 1) & 3);
    kq[i] = Kb + (size_t)kk * (SEGL * 32) + (size_t)r * 32 + gg * 8;
    int rv = ch * 8 + (lane >> 3);
    int gv = (lane & 7) ^ (rv & 7);
    vq[i] = Vb + (size_t)rv * SEGL + gv * 8;
  }

  bf16x8 Qf[2][5];
#pragma unroll
  for (int sni = 0; sni < 2; sni++)
#pragma unroll
    for (int kk = 0; kk < 5; kk++) {
      int qr = q0 + wave * 64 + sni * 32 + c;
      Qf[sni][kk] = *(const bf16x8*)&Qb[(size_t)(kk >> 1) * (SEGL * 32) +
                                        (size_t)qr * 32 + ((kk & 1) * 2 + hi) * 8];
    }

#pragma unroll
  for (int i = 0; i < 3; i++) {
    gload16(kq[i], (char*)sK[0] + (wave * 3 + i) * 1024);
    gload16(vq[i], (char*)sV[0] + (wave * 3 + i) * 1024);
    kq[i] += 2048;
    vq[i] += 64;
  }
  __syncthreads();

  f32x16 accO[3][2];
#pragma unroll
  for (int df = 0; df < 3; df++)
#pragma unroll
    for (int sni = 0; sni < 2; sni++)
#pragma unroll
      for (int r = 0; r < 16; r++) accO[df][sni][r] = 0.f;
  f32x16 ZC;
#pragma unroll
  for (int r = 0; r < 16; r++) ZC[r] = 0.f;

  int cur = 0;
  for (int tile = 0; tile < 32; ++tile) {
    if (tile + 1 < 32) {
#pragma unroll
      for (int i = 0; i < 3; i++) {
        gload16(kq[i], (char*)sK[cur ^ 1] + (wave * 3 + i) * 1024);
        gload16(vq[i], (char*)sV[cur ^ 1] + (wave * 3 + i) * 1024);
        kq[i] += 2048;
        vq[i] += 64;
      }
    }

    // ===== S^T = K · Q =====
    f32x16 S[2][2];
    __builtin_amdgcn_s_setprio(1);
#pragma unroll
    for (int kk = 0; kk < 5; kk++) {
      bf16x8 Kf[2];
#pragma unroll
      for (int smi = 0; smi < 2; smi++) {
        int kr = smi * 32 + c;
        int gg = (((kk & 1) * 2 + hi) ^ ((kr >> 1) & 3));
        Kf[smi] = *(const bf16x8*)&sK[cur][(kk >> 1) * 2048 + kr * 32 + gg * 8];
      }
#pragma unroll
      for (int smi = 0; smi < 2; smi++)
#pragma unroll
        for (int sni = 0; sni < 2; sni++)
          S[smi][sni] = __builtin_amdgcn_mfma_f32_32x32x16_bf16(
              Kf[smi], Qf[sni][kk], kk ? S[smi][sni] : ZC, 0, 0, 0);
    }
    __builtin_amdgcn_s_setprio(0);

    // ===== O^T += V^T · P^T =====
    __builtin_amdgcn_s_setprio(1);
#pragma unroll
    for (int kk = 0; kk < 4; kk++) {
      bf16x8 Vf[3];
#pragma unroll
      for (int df = 0; df < 3; df++) {
        int dr = df * 32 + c;
        int gg = ((kk * 2 + hi) ^ (dr & 7));
        Vf[df] = *(const bf16x8*)&sV[cur][dr * 64 + gg * 8];
      }
#pragma unroll
      for (int sni = 0; sni < 2; sni++) {
        const int smi = kk >> 1;
        const int base = (kk & 1) * 8;
        unsigned u0 = cvtpk(__builtin_amdgcn_exp2f(S[smi][sni][base + 0]),
                            __builtin_amdgcn_exp2f(S[smi][sni][base + 1]));
        unsigned u1 = cvtpk(__builtin_amdgcn_exp2f(S[smi][sni][base + 2]),
                            __builtin_amdgcn_exp2f(S[smi][sni][base + 3]));
        unsigned u2 = cvtpk(__builtin_amdgcn_exp2f(S[smi][sni][base + 4]),
                            __builtin_amdgcn_exp2f(S[smi][sni][base + 5]));
        unsigned u3 = cvtpk(__builtin_amdgcn_exp2f(S[smi][sni][base + 6]),
                            __builtin_amdgcn_exp2f(S[smi][sni][base + 7]));
        asm volatile("v_permlane32_swap_b32 %0, %1" : "+v"(u0), "+v"(u2));
        asm volatile("v_permlane32_swap_b32 %0, %1" : "+v"(u1), "+v"(u3));
        union { bf16x8 v; unsigned u[4]; } pb;
        pb.u[0] = u0; pb.u[1] = u1; pb.u[2] = u2; pb.u[3] = u3;
#pragma unroll
        for (int df = 0; df < 3; df++)
          accO[df][sni] = __builtin_amdgcn_mfma_f32_32x32x16_bf16(Vf[df], pb.v, accO[df][sni], 0, 0, 0);
      }
    }
    __builtin_amdgcn_s_setprio(0);

    __syncthreads();
    cur ^= 1;
  }

  // ===== write O (token-major), 8 B packed stores =====
#pragma unroll
  for (int sni = 0; sni < 2; sni++) {
    float lown = accO[2][sni][4];
    float lv = lown + __shfl_xor(lown, 32, 64);
    float inv = 1.f / lv;
    int token = s * SEGL + q0 + wave * 64 + sni * 32 + c;
#pragma unroll
    for (int df = 0; df < 3; df++)
#pragma unroll
      for (int rg = 0; rg < 4; rg++) {
        int d0 = df * 32 + rg * 8 + hi * 4;
        if (d0 < HD) {
          uint2_t w;
          w[0] = cvtpk(accO[df][sni][rg * 4 + 0] * inv, accO[df][sni][rg * 4 + 1] * inv);
          w[1] = cvtpk(accO[df][sni][rg * 4 + 2] * inv, accO[df][sni][rg * 4 + 3] * inv);
          *(uint2_t*)&Oo[(size_t)token * DIMM + h * HD + d0] = w;
        }
      }
  }
}

// -------------------------------------------------------------------------------
extern "C" void kernel_launch(void* const* d_in, const int* in_sizes, int n_in,
                              void* d_out, int out_size, void* d_ws, size_t ws_size,
                              hipStream_t stream) {
  (void)in_sizes; (void)n_in; (void)out_size; (void)ws_size;
  const float* hs     = (const float*)d_in[0];
  const float* cosp   = (const float*)d_in[1];
  const float* sinp   = (const float*)d_in[2];
  const float* w_qkv  = (const float*)d_in[4];
  const float* b_qkv  = (const float*)d_in[5];
  const float* w_proj = (const float*)d_in[6];
  const float* b_proj = (const float*)d_in[7];
  float* out = (float*)d_out;

  char* ws = (char*)d_ws;
  bf16* hsb    = (bf16*)(ws + 0);          // 18874368
  bf16* wprojT = (bf16*)(ws + 26836992);   //  2654208
  bf16* qkv    = (bf16*)(ws + 29491200);   // 56623104
  bf16* Qp     = (bf16*)(ws + 86114304);   // 25165824
  bf16* Kp     = (bf16*)(ws + 111280128);  // 25165824
  bf16* Vt     = (bf16*)(ws + 136445952);  // 25165824
  bf16* ao     = (bf16*)(ws + 161611776);  // 18874368
  // wqkvT (padded to 3584 rows) aliases ao: its lifetime ends before attn.
  bf16* wqkvT  = (bf16*)(ws + 161611776);

  k_prep<<<5940, 256, 0, stream>>>(hs, hsb, w_qkv, wqkvT, w_proj, wprojT);
  k_gemm8<false><<<448, 512, 0, stream>>>(hsb, wqkvT, b_qkv, (void*)qkv, 8192, 3456, 1152, 14);
  k_ropev<<<4096, 256, 0, stream>>>(qkv, cosp, sinp, Qp, Kp, Vt);
  k_attn<<<512, 256, 0, stream>>>(Qp, Kp, Vt, ao);
  k_gemmP<128, 128, 4, 4, 256, true><<<576, 256, 0, stream>>>(
      ao, wprojT, b_proj, (void*)out, 8192, 1152, 1152, 9);
}